// Round 1
// baseline (706.197 us; speedup 1.0000x reference)
//
#include <hip/hip_runtime.h>
#include <math.h>

#define D_MODEL 1024
#define HEAD 64
#define BATCH 4
#define SEQ 2048
#define M_TOT (BATCH*SEQ)   // 8192

// ---------------- QKV projection ----------------
// grid: M_TOT/32 = 256 blocks, 256 threads each.
// Computes Q,K,V [M_TOT][64] fp32 into workspace.
#define BMR 32
#define KC 32
#define XS_STR 36
#define WL_STR 196

__global__ __launch_bounds__(256) void qkv_proj_kernel(
    const float* __restrict__ x,
    const float* __restrict__ wq, const float* __restrict__ bq,
    const float* __restrict__ wk, const float* __restrict__ bk,
    const float* __restrict__ wv, const float* __restrict__ bv,
    float* __restrict__ Qw, float* __restrict__ Kw, float* __restrict__ Vw)
{
    __shared__ float xs[BMR][XS_STR];
    __shared__ float wl[KC][WL_STR];
    const int t  = threadIdx.x;
    const int m0 = blockIdx.x * BMR;
    const int tr = t >> 4;   // 0..15  -> rows 2*tr, 2*tr+1
    const int tc = t & 15;   // 0..15  -> cols tc*4..tc*4+3 per matrix

    float acc[2][12];
#pragma unroll
    for (int r = 0; r < 2; ++r)
#pragma unroll
        for (int j = 0; j < 12; ++j) acc[r][j] = 0.f;

    for (int k0 = 0; k0 < D_MODEL; k0 += KC) {
        __syncthreads();
        // stage x tile [32 rows][32 k]
        {
            int i = t >> 3, kq = t & 7;
            float4 v = *(const float4*)&x[(size_t)(m0 + i) * D_MODEL + k0 + kq * 4];
            *(float4*)&xs[i][kq * 4] = v;
        }
        // stage weights [KC][192] (q|k|v concatenated along cols)
#pragma unroll
        for (int rep = 0; rep < 6; ++rep) {
            int lin = rep * 256 + t;       // 0..1535 float4s
            int k   = lin / 48;            // 0..31
            int cg  = lin - k * 48;        // 0..47
            int mat = cg >> 4, c4 = cg & 15;
            const float* wsrc = (mat == 0) ? wq : ((mat == 1) ? wk : wv);
            float4 v = *(const float4*)&wsrc[(size_t)(k0 + k) * HEAD + c4 * 4];
            *(float4*)&wl[k][mat * 64 + c4 * 4] = v;
        }
        __syncthreads();
#pragma unroll
        for (int k = 0; k < KC; ++k) {
            float xa = xs[tr * 2 + 0][k];
            float xb = xs[tr * 2 + 1][k];
#pragma unroll
            for (int mm = 0; mm < 3; ++mm) {
                float4 w4 = *(const float4*)&wl[k][mm * 64 + tc * 4];
                acc[0][mm*4+0] += xa * w4.x; acc[0][mm*4+1] += xa * w4.y;
                acc[0][mm*4+2] += xa * w4.z; acc[0][mm*4+3] += xa * w4.w;
                acc[1][mm*4+0] += xb * w4.x; acc[1][mm*4+1] += xb * w4.y;
                acc[1][mm*4+2] += xb * w4.z; acc[1][mm*4+3] += xb * w4.w;
            }
        }
    }
    // epilogue: + bias, store
    {
        float4 bb = *(const float4*)&bq[tc * 4];
#pragma unroll
        for (int r = 0; r < 2; ++r) {
            int m = m0 + tr * 2 + r;
            float4 o;
            o.x = acc[r][0] + bb.x; o.y = acc[r][1] + bb.y;
            o.z = acc[r][2] + bb.z; o.w = acc[r][3] + bb.w;
            *(float4*)&Qw[(size_t)m * HEAD + tc * 4] = o;
        }
    }
    {
        float4 bb = *(const float4*)&bk[tc * 4];
#pragma unroll
        for (int r = 0; r < 2; ++r) {
            int m = m0 + tr * 2 + r;
            float4 o;
            o.x = acc[r][4] + bb.x; o.y = acc[r][5] + bb.y;
            o.z = acc[r][6] + bb.z; o.w = acc[r][7] + bb.w;
            *(float4*)&Kw[(size_t)m * HEAD + tc * 4] = o;
        }
    }
    {
        float4 bb = *(const float4*)&bv[tc * 4];
#pragma unroll
        for (int r = 0; r < 2; ++r) {
            int m = m0 + tr * 2 + r;
            float4 o;
            o.x = acc[r][8]  + bb.x; o.y = acc[r][9]  + bb.y;
            o.z = acc[r][10] + bb.z; o.w = acc[r][11] + bb.w;
            *(float4*)&Vw[(size_t)m * HEAD + tc * 4] = o;
        }
    }
}

// ---------------- Flash causal attention (fp32) ----------------
// 64-thread blocks. Each block processes two 16-row q-chunks: qq and 127-qq
// (causal load balancing: each block handles ~33 KV tiles of 64).
// lane l: row r = l>>2 within chunk; quarter h = l&3 -> dims [16h,16h+16).
__global__ __launch_bounds__(64) void attn_kernel(
    const float* __restrict__ Qw, const float* __restrict__ Kw,
    const float* __restrict__ Vw, float* __restrict__ out)
{
    __shared__ float Ks[64][HEAD];
    __shared__ float Vs[64][HEAD];
    const int l  = threadIdx.x;
    const int b  = blockIdx.y;
    const int qq = blockIdx.x;     // 0..63

    const int r  = l >> 2;
    const int h  = l & 3;
    const int hd = h * 16;

#pragma unroll 1
    for (int half = 0; half < 2; ++half) {
        const int chunk = (half == 0) ? qq : (127 - qq);
        const int q0   = chunk * 16;
        const int grow = q0 + r;

        // load q row-fragment into registers
        const float* qptr = &Qw[(size_t)(b * SEQ + grow) * HEAD + hd];
        float q[16];
#pragma unroll
        for (int j4 = 0; j4 < 4; ++j4) {
            float4 v = *(const float4*)&qptr[j4 * 4];
            q[j4*4+0] = v.x; q[j4*4+1] = v.y; q[j4*4+2] = v.z; q[j4*4+3] = v.w;
        }
        float o[16];
#pragma unroll
        for (int j = 0; j < 16; ++j) o[j] = 0.f;
        float mrun = -1e30f, lsum = 0.f;

        const int ntiles = (q0 + 16 + 63) >> 6;
        for (int tile = 0; tile < ntiles; ++tile) {
            const int c0 = tile * 64;
            __syncthreads();
            // stage K,V tile [64][64]
#pragma unroll
            for (int it = 0; it < 16; ++it) {
                int idx = it * 64 + l;
                int row = idx >> 4, c4 = idx & 15;
                size_t gbase = (size_t)(b * SEQ + c0 + row) * HEAD + c4 * 4;
                *(float4*)&Ks[row][c4 * 4] = *(const float4*)&Kw[gbase];
                *(float4*)&Vs[row][c4 * 4] = *(const float4*)&Vw[gbase];
            }
            __syncthreads();

            // scores for this lane's row, 16-dim partial then 4-lane reduce
            float sc[64];
            float tmax = -1e30f;
#pragma unroll
            for (int c = 0; c < 64; ++c) {
                const float4* kr = (const float4*)&Ks[c][hd];
                float4 a0 = kr[0], a1 = kr[1], a2 = kr[2], a3 = kr[3];
                float s;
                s  = q[0]  * a0.x; s += q[1]  * a0.y; s += q[2]  * a0.z; s += q[3]  * a0.w;
                s += q[4]  * a1.x; s += q[5]  * a1.y; s += q[6]  * a1.z; s += q[7]  * a1.w;
                s += q[8]  * a2.x; s += q[9]  * a2.y; s += q[10] * a2.z; s += q[11] * a2.w;
                s += q[12] * a3.x; s += q[13] * a3.y; s += q[14] * a3.z; s += q[15] * a3.w;
                s += __shfl_xor(s, 1);
                s += __shfl_xor(s, 2);
                s *= 8.0f;   // * sqrt(HEAD), faithful to reference
                if (c0 + c > grow) s = -1e30f;
                sc[c] = s;
                tmax = fmaxf(tmax, s);
            }
            float newm = fmaxf(mrun, tmax);
            float corr = __expf(mrun - newm);
            lsum *= corr;
#pragma unroll
            for (int j = 0; j < 16; ++j) o[j] *= corr;
#pragma unroll
            for (int c = 0; c < 64; ++c) {
                float p = __expf(sc[c] - newm);
                lsum += p;
                const float4* vr = (const float4*)&Vs[c][hd];
                float4 v0 = vr[0], v1 = vr[1], v2 = vr[2], v3 = vr[3];
                o[0]  += p * v0.x; o[1]  += p * v0.y; o[2]  += p * v0.z; o[3]  += p * v0.w;
                o[4]  += p * v1.x; o[5]  += p * v1.y; o[6]  += p * v1.z; o[7]  += p * v1.w;
                o[8]  += p * v2.x; o[9]  += p * v2.y; o[10] += p * v2.z; o[11] += p * v2.w;
                o[12] += p * v3.x; o[13] += p * v3.y; o[14] += p * v3.z; o[15] += p * v3.w;
            }
            mrun = newm;
        }

        float inv = 1.0f / lsum;
        float* optr = &out[(size_t)(b * SEQ + grow) * HEAD + hd];
#pragma unroll
        for (int j4 = 0; j4 < 4; ++j4) {
            float4 v;
            v.x = o[j4*4+0] * inv; v.y = o[j4*4+1] * inv;
            v.z = o[j4*4+2] * inv; v.w = o[j4*4+3] * inv;
            *(float4*)&optr[j4 * 4] = v;
        }
    }
}

extern "C" void kernel_launch(void* const* d_in, const int* in_sizes, int n_in,
                              void* d_out, int out_size, void* d_ws, size_t ws_size,
                              hipStream_t stream) {
    (void)in_sizes; (void)n_in; (void)out_size; (void)ws_size;
    const float* x  = (const float*)d_in[0];
    const float* wq = (const float*)d_in[1];
    const float* bq = (const float*)d_in[2];
    const float* wk = (const float*)d_in[3];
    const float* bk = (const float*)d_in[4];
    const float* wv = (const float*)d_in[5];
    const float* bv = (const float*)d_in[6];
    float* out = (float*)d_out;

    float* Qw = (float*)d_ws;                       // [M_TOT][64]
    float* Kw = Qw + (size_t)M_TOT * HEAD;          // [M_TOT][64]
    float* Vw = Kw + (size_t)M_TOT * HEAD;          // [M_TOT][64]  (needs 6 MB ws)

    hipLaunchKernelGGL(qkv_proj_kernel, dim3(M_TOT / BMR), dim3(256), 0, stream,
                       x, wq, bq, wk, bk, wv, bv, Qw, Kw, Vw);
    hipLaunchKernelGGL(attn_kernel, dim3(64, BATCH), dim3(64), 0, stream,
                       Qw, Kw, Vw, out);
}

// Round 2
// 550.545 us; speedup vs baseline: 1.2827x; 1.2827x over previous
//
#include <hip/hip_runtime.h>
#include <math.h>

#define D_MODEL 1024
#define HEAD 64
#define BATCH 4
#define SEQ 2048
#define M_TOT (BATCH*SEQ)   // 8192

// ---------------- QKV projection ----------------
// grid: M_TOT/32 = 256 blocks, 256 threads each.
#define BMR 32
#define KC 32
#define XS_STR 36
#define WL_STR 196

__global__ __launch_bounds__(256) void qkv_proj_kernel(
    const float* __restrict__ x,
    const float* __restrict__ wq, const float* __restrict__ bq,
    const float* __restrict__ wk, const float* __restrict__ bk,
    const float* __restrict__ wv, const float* __restrict__ bv,
    float* __restrict__ Qw, float* __restrict__ Kw, float* __restrict__ Vw)
{
    __shared__ float xs[BMR][XS_STR];
    __shared__ float wl[KC][WL_STR];
    const int t  = threadIdx.x;
    const int m0 = blockIdx.x * BMR;
    const int tr = t >> 4;
    const int tc = t & 15;

    float acc[2][12];
#pragma unroll
    for (int r = 0; r < 2; ++r)
#pragma unroll
        for (int j = 0; j < 12; ++j) acc[r][j] = 0.f;

    for (int k0 = 0; k0 < D_MODEL; k0 += KC) {
        __syncthreads();
        {
            int i = t >> 3, kq = t & 7;
            float4 v = *(const float4*)&x[(size_t)(m0 + i) * D_MODEL + k0 + kq * 4];
            *(float4*)&xs[i][kq * 4] = v;
        }
#pragma unroll
        for (int rep = 0; rep < 6; ++rep) {
            int lin = rep * 256 + t;
            int k   = lin / 48;
            int cg  = lin - k * 48;
            int mat = cg >> 4, c4 = cg & 15;
            const float* wsrc = (mat == 0) ? wq : ((mat == 1) ? wk : wv);
            float4 v = *(const float4*)&wsrc[(size_t)(k0 + k) * HEAD + c4 * 4];
            *(float4*)&wl[k][mat * 64 + c4 * 4] = v;
        }
        __syncthreads();
#pragma unroll
        for (int k = 0; k < KC; ++k) {
            float xa = xs[tr * 2 + 0][k];
            float xb = xs[tr * 2 + 1][k];
#pragma unroll
            for (int mm = 0; mm < 3; ++mm) {
                float4 w4 = *(const float4*)&wl[k][mm * 64 + tc * 4];
                acc[0][mm*4+0] += xa * w4.x; acc[0][mm*4+1] += xa * w4.y;
                acc[0][mm*4+2] += xa * w4.z; acc[0][mm*4+3] += xa * w4.w;
                acc[1][mm*4+0] += xb * w4.x; acc[1][mm*4+1] += xb * w4.y;
                acc[1][mm*4+2] += xb * w4.z; acc[1][mm*4+3] += xb * w4.w;
            }
        }
    }
    {
        float4 bb = *(const float4*)&bq[tc * 4];
#pragma unroll
        for (int r = 0; r < 2; ++r) {
            int m = m0 + tr * 2 + r;
            float4 o;
            o.x = acc[r][0] + bb.x; o.y = acc[r][1] + bb.y;
            o.z = acc[r][2] + bb.z; o.w = acc[r][3] + bb.w;
            *(float4*)&Qw[(size_t)m * HEAD + tc * 4] = o;
        }
    }
    {
        float4 bb = *(const float4*)&bk[tc * 4];
#pragma unroll
        for (int r = 0; r < 2; ++r) {
            int m = m0 + tr * 2 + r;
            float4 o;
            o.x = acc[r][4] + bb.x; o.y = acc[r][5] + bb.y;
            o.z = acc[r][6] + bb.z; o.w = acc[r][7] + bb.w;
            *(float4*)&Kw[(size_t)m * HEAD + tc * 4] = o;
        }
    }
    {
        float4 bb = *(const float4*)&bv[tc * 4];
#pragma unroll
        for (int r = 0; r < 2; ++r) {
            int m = m0 + tr * 2 + r;
            float4 o;
            o.x = acc[r][8]  + bb.x; o.y = acc[r][9]  + bb.y;
            o.z = acc[r][10] + bb.z; o.w = acc[r][11] + bb.w;
            *(float4*)&Vw[(size_t)m * HEAD + tc * 4] = o;
        }
    }
}

// ---------------- Flash causal attention (fp32, split-KV) ----------------
// Block = 256 threads = 4 waves, one 16-row q-chunk per block.
// Wave w handles KV tiles w, w+4, w+8, ... with private online-softmax state;
// partials merged through LDS at the end.
// Lane l: row r = l>>2 (16 rows/wave), quarter h = l&3 -> dims [16h, 16h+16).
#define NW 4
#define CHUNK 16

__global__ __launch_bounds__(256) void attn_kernel(
    const float* __restrict__ Qw, const float* __restrict__ Kw,
    const float* __restrict__ Vw, float* __restrict__ out)
{
    __shared__ float Po[NW][CHUNK][HEAD];   // 16 KB partial O
    __shared__ float Pm[NW][CHUNK];
    __shared__ float Pl[NW][CHUNK];

    const int t = threadIdx.x;
    const int w = t >> 6;          // wave 0..3
    const int l = t & 63;
    const int b = blockIdx.y;
    const int chunk = (int)gridDim.x - 1 - (int)blockIdx.x;  // biggest work first
    const int q0 = chunk * CHUNK;

    const int r  = l >> 2;
    const int h  = l & 3;
    const int hd = h * 16;
    const int grow = q0 + r;

    // q row-fragment in registers
    const float* qptr = &Qw[(size_t)(b * SEQ + grow) * HEAD + hd];
    float q[16];
#pragma unroll
    for (int j4 = 0; j4 < 4; ++j4) {
        float4 v = *(const float4*)&qptr[j4 * 4];
        q[j4*4+0] = v.x; q[j4*4+1] = v.y; q[j4*4+2] = v.z; q[j4*4+3] = v.w;
    }
    float o[16];
#pragma unroll
    for (int j = 0; j < 16; ++j) o[j] = 0.f;
    float mrun = -1e30f, lsum = 0.f;

    const int ntiles = (q0 + CHUNK + 63) >> 6;
    for (int tile = w; tile < ntiles; tile += NW) {
        const int c0 = tile * 64;
        const float* Kbase = &Kw[(size_t)(b * SEQ + c0) * HEAD + hd];
        const float* Vbase = &Vw[(size_t)(b * SEQ + c0) * HEAD + hd];

        float sc[64];
        float tmax = -1e30f;
#pragma unroll 8
        for (int c = 0; c < 64; ++c) {
            const float4* kr = (const float4*)(Kbase + (size_t)c * HEAD);
            float4 a0 = kr[0], a1 = kr[1], a2 = kr[2], a3 = kr[3];
            float s;
            s  = q[0]  * a0.x; s += q[1]  * a0.y; s += q[2]  * a0.z; s += q[3]  * a0.w;
            s += q[4]  * a1.x; s += q[5]  * a1.y; s += q[6]  * a1.z; s += q[7]  * a1.w;
            s += q[8]  * a2.x; s += q[9]  * a2.y; s += q[10] * a2.z; s += q[11] * a2.w;
            s += q[12] * a3.x; s += q[13] * a3.y; s += q[14] * a3.z; s += q[15] * a3.w;
            s += __shfl_xor(s, 1);
            s += __shfl_xor(s, 2);
            s *= 8.0f;                       // * sqrt(HEAD), faithful to reference
            if (c0 + c > grow) s = -1e30f;
            sc[c] = s;
            tmax = fmaxf(tmax, s);
        }
        float newm = fmaxf(mrun, tmax);
        float corr = __expf(mrun - newm);
        lsum *= corr;
#pragma unroll
        for (int j = 0; j < 16; ++j) o[j] *= corr;
#pragma unroll 8
        for (int c = 0; c < 64; ++c) {
            float p = __expf(sc[c] - newm);
            lsum += p;
            const float4* vr = (const float4*)(Vbase + (size_t)c * HEAD);
            float4 v0 = vr[0], v1 = vr[1], v2 = vr[2], v3 = vr[3];
            o[0]  += p * v0.x; o[1]  += p * v0.y; o[2]  += p * v0.z; o[3]  += p * v0.w;
            o[4]  += p * v1.x; o[5]  += p * v1.y; o[6]  += p * v1.z; o[7]  += p * v1.w;
            o[8]  += p * v2.x; o[9]  += p * v2.y; o[10] += p * v2.z; o[11] += p * v2.w;
            o[12] += p * v3.x; o[13] += p * v3.y; o[14] += p * v3.z; o[15] += p * v3.w;
        }
        mrun = newm;
    }

    // publish partials (all 4 lanes of a row hold identical m/l -> benign dup store)
    Pm[w][r] = mrun;
    Pl[w][r] = lsum;
#pragma unroll
    for (int j4 = 0; j4 < 4; ++j4) {
        float4 v;
        v.x = o[j4*4+0]; v.y = o[j4*4+1]; v.z = o[j4*4+2]; v.w = o[j4*4+3];
        *(float4*)&Po[w][r][hd + j4 * 4] = v;
    }
    __syncthreads();

    // merge: thread t -> row mr = t>>4, dims md..md+3
    const int mr = t >> 4;
    const int md = (t & 15) * 4;
    float M = Pm[0][mr];
#pragma unroll
    for (int ww = 1; ww < NW; ++ww) M = fmaxf(M, Pm[ww][mr]);
    float L = 0.f;
    float4 O; O.x = O.y = O.z = O.w = 0.f;
#pragma unroll
    for (int ww = 0; ww < NW; ++ww) {
        float f = __expf(Pm[ww][mr] - M);
        L += f * Pl[ww][mr];
        float4 p = *(const float4*)&Po[ww][mr][md];
        O.x += f * p.x; O.y += f * p.y; O.z += f * p.z; O.w += f * p.w;
    }
    float inv = 1.0f / L;
    float4 res; res.x = O.x * inv; res.y = O.y * inv; res.z = O.z * inv; res.w = O.w * inv;
    *(float4*)&out[(size_t)(b * SEQ + q0 + mr) * HEAD + md] = res;
}

extern "C" void kernel_launch(void* const* d_in, const int* in_sizes, int n_in,
                              void* d_out, int out_size, void* d_ws, size_t ws_size,
                              hipStream_t stream) {
    (void)in_sizes; (void)n_in; (void)out_size; (void)ws_size;
    const float* x  = (const float*)d_in[0];
    const float* wq = (const float*)d_in[1];
    const float* bq = (const float*)d_in[2];
    const float* wk = (const float*)d_in[3];
    const float* bk = (const float*)d_in[4];
    const float* wv = (const float*)d_in[5];
    const float* bv = (const float*)d_in[6];
    float* out = (float*)d_out;

    float* Qw = (float*)d_ws;                       // [M_TOT][64]
    float* Kw = Qw + (size_t)M_TOT * HEAD;          // [M_TOT][64]
    float* Vw = Kw + (size_t)M_TOT * HEAD;          // [M_TOT][64]  (6 MB of ws)

    hipLaunchKernelGGL(qkv_proj_kernel, dim3(M_TOT / BMR), dim3(256), 0, stream,
                       x, wq, bq, wk, bk, wv, bv, Qw, Kw, Vw);
    hipLaunchKernelGGL(attn_kernel, dim3(SEQ / CHUNK, BATCH), dim3(256), 0, stream,
                       Qw, Kw, Vw, out);
}

// Round 3
// 513.742 us; speedup vs baseline: 1.3746x; 1.0716x over previous
//
#include <hip/hip_runtime.h>
#include <math.h>

#define D_MODEL 1024
#define HEAD 64
#define BATCH 4
#define SEQ 2048
#define M_TOT (BATCH*SEQ)   // 8192

// ---------------- QKV projection ----------------
#define BMR 32
#define KC 32
#define XS_STR 36
#define WL_STR 196

__global__ __launch_bounds__(256) void qkv_proj_kernel(
    const float* __restrict__ x,
    const float* __restrict__ wq, const float* __restrict__ bq,
    const float* __restrict__ wk, const float* __restrict__ bk,
    const float* __restrict__ wv, const float* __restrict__ bv,
    float* __restrict__ Qw, float* __restrict__ Kw, float* __restrict__ Vw)
{
    __shared__ float xs[BMR][XS_STR];
    __shared__ float wl[KC][WL_STR];
    const int t  = threadIdx.x;
    const int m0 = blockIdx.x * BMR;
    const int tr = t >> 4;
    const int tc = t & 15;

    float acc[2][12];
#pragma unroll
    for (int r = 0; r < 2; ++r)
#pragma unroll
        for (int j = 0; j < 12; ++j) acc[r][j] = 0.f;

    for (int k0 = 0; k0 < D_MODEL; k0 += KC) {
        __syncthreads();
        {
            int i = t >> 3, kq = t & 7;
            float4 v = *(const float4*)&x[(size_t)(m0 + i) * D_MODEL + k0 + kq * 4];
            *(float4*)&xs[i][kq * 4] = v;
        }
#pragma unroll
        for (int rep = 0; rep < 6; ++rep) {
            int lin = rep * 256 + t;
            int k   = lin / 48;
            int cg  = lin - k * 48;
            int mat = cg >> 4, c4 = cg & 15;
            const float* wsrc = (mat == 0) ? wq : ((mat == 1) ? wk : wv);
            float4 v = *(const float4*)&wsrc[(size_t)(k0 + k) * HEAD + c4 * 4];
            *(float4*)&wl[k][mat * 64 + c4 * 4] = v;
        }
        __syncthreads();
#pragma unroll
        for (int k = 0; k < KC; ++k) {
            float xa = xs[tr * 2 + 0][k];
            float xb = xs[tr * 2 + 1][k];
#pragma unroll
            for (int mm = 0; mm < 3; ++mm) {
                float4 w4 = *(const float4*)&wl[k][mm * 64 + tc * 4];
                acc[0][mm*4+0] += xa * w4.x; acc[0][mm*4+1] += xa * w4.y;
                acc[0][mm*4+2] += xa * w4.z; acc[0][mm*4+3] += xa * w4.w;
                acc[1][mm*4+0] += xb * w4.x; acc[1][mm*4+1] += xb * w4.y;
                acc[1][mm*4+2] += xb * w4.z; acc[1][mm*4+3] += xb * w4.w;
            }
        }
    }
    {
        float4 bb = *(const float4*)&bq[tc * 4];
#pragma unroll
        for (int r = 0; r < 2; ++r) {
            int m = m0 + tr * 2 + r;
            float4 o;
            o.x = acc[r][0] + bb.x; o.y = acc[r][1] + bb.y;
            o.z = acc[r][2] + bb.z; o.w = acc[r][3] + bb.w;
            *(float4*)&Qw[(size_t)m * HEAD + tc * 4] = o;
        }
    }
    {
        float4 bb = *(const float4*)&bk[tc * 4];
#pragma unroll
        for (int r = 0; r < 2; ++r) {
            int m = m0 + tr * 2 + r;
            float4 o;
            o.x = acc[r][4] + bb.x; o.y = acc[r][5] + bb.y;
            o.z = acc[r][6] + bb.z; o.w = acc[r][7] + bb.w;
            *(float4*)&Kw[(size_t)m * HEAD + tc * 4] = o;
        }
    }
    {
        float4 bb = *(const float4*)&bv[tc * 4];
#pragma unroll
        for (int r = 0; r < 2; ++r) {
            int m = m0 + tr * 2 + r;
            float4 o;
            o.x = acc[r][8]  + bb.x; o.y = acc[r][9]  + bb.y;
            o.z = acc[r][10] + bb.z; o.w = acc[r][11] + bb.w;
            *(float4*)&Vw[(size_t)m * HEAD + tc * 4] = o;
        }
    }
}

// ---------------- Flash causal attention (fp32, split-KV) ----------------
// Block = 256 threads = 4 waves, one 16-row q-chunk per block.
// Wave w handles KV tiles w, w+4, ... with private online-softmax state.
// Each 64-col tile is processed as 4x 16-col sub-tiles so the score array
// sc16[16] stays fully statically indexed -> registers (no scratch).
// Lane l: row r = l>>2 (16 rows/wave), quarter h = l&3 -> dims [16h, 16h+16).
#define NW 4
#define CHUNK 16

__global__ __launch_bounds__(256) void attn_kernel(
    const float* __restrict__ Qw, const float* __restrict__ Kw,
    const float* __restrict__ Vw, float* __restrict__ out)
{
    __shared__ float Po[NW][CHUNK][HEAD];
    __shared__ float Pm[NW][CHUNK];
    __shared__ float Pl[NW][CHUNK];

    const int t = threadIdx.x;
    const int w = t >> 6;
    const int l = t & 63;
    const int b = blockIdx.y;
    const int chunk = (int)gridDim.x - 1 - (int)blockIdx.x;  // biggest work first
    const int q0 = chunk * CHUNK;

    const int r  = l >> 2;
    const int h  = l & 3;
    const int hd = h * 16;
    const int grow = q0 + r;

    const float* qptr = &Qw[(size_t)(b * SEQ + grow) * HEAD + hd];
    float q[16];
#pragma unroll
    for (int j4 = 0; j4 < 4; ++j4) {
        float4 v = *(const float4*)&qptr[j4 * 4];
        q[j4*4+0] = v.x; q[j4*4+1] = v.y; q[j4*4+2] = v.z; q[j4*4+3] = v.w;
    }
    float o[16];
#pragma unroll
    for (int j = 0; j < 16; ++j) o[j] = 0.f;
    float mrun = -1e30f, lsum = 0.f;

    const int ntiles = (q0 + CHUNK + 63) >> 6;
#pragma unroll 1
    for (int tile = w; tile < ntiles; tile += NW) {
        const int c0 = tile * 64;
        const float* Kbase = &Kw[(size_t)(b * SEQ + c0) * HEAD + hd];
        const float* Vbase = &Vw[(size_t)(b * SEQ + c0) * HEAD + hd];

#pragma unroll 1
        for (int cc = 0; cc < 4; ++cc) {
            const int cb = cc * 16;
            if (c0 + cb > q0 + CHUNK - 1) break;   // wave-uniform: fully masked

            float sc16[16];
            float tmax = -1e30f;
#pragma unroll
            for (int c = 0; c < 16; ++c) {
                const float4* kr = (const float4*)(Kbase + (size_t)(cb + c) * HEAD);
                float4 a0 = kr[0], a1 = kr[1], a2 = kr[2], a3 = kr[3];
                float s;
                s  = q[0]  * a0.x; s += q[1]  * a0.y; s += q[2]  * a0.z; s += q[3]  * a0.w;
                s += q[4]  * a1.x; s += q[5]  * a1.y; s += q[6]  * a1.z; s += q[7]  * a1.w;
                s += q[8]  * a2.x; s += q[9]  * a2.y; s += q[10] * a2.z; s += q[11] * a2.w;
                s += q[12] * a3.x; s += q[13] * a3.y; s += q[14] * a3.z; s += q[15] * a3.w;
                s += __shfl_xor(s, 1);
                s += __shfl_xor(s, 2);
                s *= 8.0f;                       // * sqrt(HEAD), faithful to reference
                if (c0 + cb + c > grow) s = -1e30f;
                sc16[c] = s;
                tmax = fmaxf(tmax, s);
            }
            float newm = fmaxf(mrun, tmax);
            float corr = __expf(mrun - newm);
            lsum *= corr;
#pragma unroll
            for (int j = 0; j < 16; ++j) o[j] *= corr;
#pragma unroll
            for (int c = 0; c < 16; ++c) {
                float p = __expf(sc16[c] - newm);
                lsum += p;
                const float4* vr = (const float4*)(Vbase + (size_t)(cb + c) * HEAD);
                float4 v0 = vr[0], v1 = vr[1], v2 = vr[2], v3 = vr[3];
                o[0]  += p * v0.x; o[1]  += p * v0.y; o[2]  += p * v0.z; o[3]  += p * v0.w;
                o[4]  += p * v1.x; o[5]  += p * v1.y; o[6]  += p * v1.z; o[7]  += p * v1.w;
                o[8]  += p * v2.x; o[9]  += p * v2.y; o[10] += p * v2.z; o[11] += p * v2.w;
                o[12] += p * v3.x; o[13] += p * v3.y; o[14] += p * v3.z; o[15] += p * v3.w;
            }
            mrun = newm;
        }
    }

    Pm[w][r] = mrun;
    Pl[w][r] = lsum;
#pragma unroll
    for (int j4 = 0; j4 < 4; ++j4) {
        float4 v;
        v.x = o[j4*4+0]; v.y = o[j4*4+1]; v.z = o[j4*4+2]; v.w = o[j4*4+3];
        *(float4*)&Po[w][r][hd + j4 * 4] = v;
    }
    __syncthreads();

    const int mr = t >> 4;
    const int md = (t & 15) * 4;
    float M = Pm[0][mr];
#pragma unroll
    for (int ww = 1; ww < NW; ++ww) M = fmaxf(M, Pm[ww][mr]);
    float L = 0.f;
    float4 O; O.x = O.y = O.z = O.w = 0.f;
#pragma unroll
    for (int ww = 0; ww < NW; ++ww) {
        float f = __expf(Pm[ww][mr] - M);
        L += f * Pl[ww][mr];
        float4 p = *(const float4*)&Po[ww][mr][md];
        O.x += f * p.x; O.y += f * p.y; O.z += f * p.z; O.w += f * p.w;
    }
    float inv = 1.0f / L;
    float4 res; res.x = O.x * inv; res.y = O.y * inv; res.z = O.z * inv; res.w = O.w * inv;
    *(float4*)&out[(size_t)(b * SEQ + q0 + mr) * HEAD + md] = res;
}

extern "C" void kernel_launch(void* const* d_in, const int* in_sizes, int n_in,
                              void* d_out, int out_size, void* d_ws, size_t ws_size,
                              hipStream_t stream) {
    (void)in_sizes; (void)n_in; (void)out_size; (void)ws_size;
    const float* x  = (const float*)d_in[0];
    const float* wq = (const float*)d_in[1];
    const float* bq = (const float*)d_in[2];
    const float* wk = (const float*)d_in[3];
    const float* bk = (const float*)d_in[4];
    const float* wv = (const float*)d_in[5];
    const float* bv = (const float*)d_in[6];
    float* out = (float*)d_out;

    float* Qw = (float*)d_ws;
    float* Kw = Qw + (size_t)M_TOT * HEAD;
    float* Vw = Kw + (size_t)M_TOT * HEAD;

    hipLaunchKernelGGL(qkv_proj_kernel, dim3(M_TOT / BMR), dim3(256), 0, stream,
                       x, wq, bq, wk, bk, wv, bv, Qw, Kw, Vw);
    hipLaunchKernelGGL(attn_kernel, dim3(SEQ / CHUNK, BATCH), dim3(256), 0, stream,
                       Qw, Kw, Vw, out);
}

// Round 4
// 120.977 us; speedup vs baseline: 5.8374x; 4.2466x over previous
//
#include <hip/hip_runtime.h>
#include <math.h>

#define D_MODEL 1024
#define HEAD 64
#define BATCH 4
#define SEQ 2048
#define M_TOT (BATCH*SEQ)   // 8192

typedef short short8 __attribute__((ext_vector_type(8)));
typedef float f32x4 __attribute__((ext_vector_type(4)));

__device__ __forceinline__ unsigned short f2bf(float x) {
    union { float f; unsigned u; } v; v.f = x;
    unsigned r = (v.u + 0x7FFFu + ((v.u >> 16) & 1u)) >> 16;
    return (unsigned short)r;
}
__device__ __forceinline__ float bf2f(unsigned short h) {
    union { unsigned u; float f; } v; v.u = ((unsigned)h) << 16;
    return v.f;
}

// ---------------- QKV projection (unchanged, fp32) ----------------
#define BMR 32
#define KC 32
#define XS_STR 36
#define WL_STR 196

__global__ __launch_bounds__(256) void qkv_proj_kernel(
    const float* __restrict__ x,
    const float* __restrict__ wq, const float* __restrict__ bq,
    const float* __restrict__ wk, const float* __restrict__ bk,
    const float* __restrict__ wv, const float* __restrict__ bv,
    float* __restrict__ Qw, float* __restrict__ Kw, float* __restrict__ Vw)
{
    __shared__ float xs[BMR][XS_STR];
    __shared__ float wl[KC][WL_STR];
    const int t  = threadIdx.x;
    const int m0 = blockIdx.x * BMR;
    const int tr = t >> 4;
    const int tc = t & 15;

    float acc[2][12];
#pragma unroll
    for (int r = 0; r < 2; ++r)
#pragma unroll
        for (int j = 0; j < 12; ++j) acc[r][j] = 0.f;

    for (int k0 = 0; k0 < D_MODEL; k0 += KC) {
        __syncthreads();
        {
            int i = t >> 3, kq = t & 7;
            float4 v = *(const float4*)&x[(size_t)(m0 + i) * D_MODEL + k0 + kq * 4];
            *(float4*)&xs[i][kq * 4] = v;
        }
#pragma unroll
        for (int rep = 0; rep < 6; ++rep) {
            int lin = rep * 256 + t;
            int k   = lin / 48;
            int cg  = lin - k * 48;
            int mat = cg >> 4, c4 = cg & 15;
            const float* wsrc = (mat == 0) ? wq : ((mat == 1) ? wk : wv);
            float4 v = *(const float4*)&wsrc[(size_t)(k0 + k) * HEAD + c4 * 4];
            *(float4*)&wl[k][mat * 64 + c4 * 4] = v;
        }
        __syncthreads();
#pragma unroll
        for (int k = 0; k < KC; ++k) {
            float xa = xs[tr * 2 + 0][k];
            float xb = xs[tr * 2 + 1][k];
#pragma unroll
            for (int mm = 0; mm < 3; ++mm) {
                float4 w4 = *(const float4*)&wl[k][mm * 64 + tc * 4];
                acc[0][mm*4+0] += xa * w4.x; acc[0][mm*4+1] += xa * w4.y;
                acc[0][mm*4+2] += xa * w4.z; acc[0][mm*4+3] += xa * w4.w;
                acc[1][mm*4+0] += xb * w4.x; acc[1][mm*4+1] += xb * w4.y;
                acc[1][mm*4+2] += xb * w4.z; acc[1][mm*4+3] += xb * w4.w;
            }
        }
    }
    {
        float4 bb = *(const float4*)&bq[tc * 4];
#pragma unroll
        for (int r = 0; r < 2; ++r) {
            int m = m0 + tr * 2 + r;
            float4 o;
            o.x = acc[r][0] + bb.x; o.y = acc[r][1] + bb.y;
            o.z = acc[r][2] + bb.z; o.w = acc[r][3] + bb.w;
            *(float4*)&Qw[(size_t)m * HEAD + tc * 4] = o;
        }
    }
    {
        float4 bb = *(const float4*)&bk[tc * 4];
#pragma unroll
        for (int r = 0; r < 2; ++r) {
            int m = m0 + tr * 2 + r;
            float4 o;
            o.x = acc[r][4] + bb.x; o.y = acc[r][5] + bb.y;
            o.z = acc[r][6] + bb.z; o.w = acc[r][7] + bb.w;
            *(float4*)&Kw[(size_t)m * HEAD + tc * 4] = o;
        }
    }
    {
        float4 bb = *(const float4*)&bv[tc * 4];
#pragma unroll
        for (int r = 0; r < 2; ++r) {
            int m = m0 + tr * 2 + r;
            float4 o;
            o.x = acc[r][8]  + bb.x; o.y = acc[r][9]  + bb.y;
            o.z = acc[r][10] + bb.z; o.w = acc[r][11] + bb.w;
            *(float4*)&Vw[(size_t)m * HEAD + tc * 4] = o;
        }
    }
}

// ---------------- V transpose: Vw fp32 [B*S][64] -> Vt bf16 [B][64][S] ----
__global__ __launch_bounds__(256) void vt_kernel(
    const float* __restrict__ Vw, unsigned short* __restrict__ Vt)
{
    __shared__ float tile[64][65];
    const int t = threadIdx.x;
    const int s0 = blockIdx.x * 64;
    const int b = blockIdx.y;
    const int col = t & 63, rq = t >> 6;
#pragma unroll
    for (int i = 0; i < 16; ++i) {
        int row = i * 4 + rq;
        tile[row][col] = Vw[(size_t)(b * SEQ + s0 + row) * HEAD + col];
    }
    __syncthreads();
#pragma unroll
    for (int i = 0; i < 16; ++i) {
        int d = i * 4 + rq;
        Vt[((size_t)(b * HEAD) + d) * SEQ + s0 + col] = f2bf(tile[col][d]);
    }
}

// ---------------- Flash causal attention (MFMA split-bf16, split-KV) ------
// Block = 256 thr = 4 waves, one 16-row q-chunk; wave w does KV64 tiles w, w+4,...
// Lane: c = l&15 (q col in S^T, d col in O), g = l>>4.
// QK^T: S^T = mfma(K_frag, Q_frag); split hi/lo on Q,K (3 mfma) for accuracy.
// PV: P routed via per-wave LDS (stride 72) to form A-frags; V^T from Vt bf16.
#define NW 4
#define CHUNK 16

__global__ __launch_bounds__(256) void attn_kernel(
    const float* __restrict__ Qw, const float* __restrict__ Kw,
    const unsigned short* __restrict__ Vt, float* __restrict__ out)
{
    __shared__ float Po[NW][CHUNK][68];
    __shared__ float Pm[NW][CHUNK];
    __shared__ float Pl[NW][CHUNK];
    __shared__ __align__(16) unsigned short Plds[NW][CHUNK][72];

    const int t = threadIdx.x;
    const int w = t >> 6;
    const int l = t & 63;
    const int b = blockIdx.y;
    const int chunk = (int)gridDim.x - 1 - (int)blockIdx.x;  // biggest first
    const int q0 = chunk * CHUNK;
    const int c = l & 15;
    const int g = l >> 4;

    // Q fragments (x8 folded in before split)
    short8 qhi[2], qlo[2];
    {
        const float* qrow = &Qw[(size_t)(b * SEQ + q0 + c) * HEAD];
#pragma unroll
        for (int dc = 0; dc < 2; ++dc) {
            const float* p4 = qrow + dc * 32 + 8 * g;
            float4 a = *(const float4*)p4;
            float4 bb = *(const float4*)(p4 + 4);
            float xs[8] = {a.x, a.y, a.z, a.w, bb.x, bb.y, bb.z, bb.w};
#pragma unroll
            for (int e = 0; e < 8; ++e) {
                float xv = xs[e] * 8.0f;
                unsigned short h = f2bf(xv);
                qhi[dc][e] = (short)h;
                qlo[dc][e] = (short)f2bf(xv - bf2f(h));
            }
        }
    }

    f32x4 acc[4];
#pragma unroll
    for (int dt = 0; dt < 4; ++dt) acc[dt] = (f32x4)0.0f;
    float mrun = -1e30f, lsum = 0.f;

    const int ntiles = (q0 + CHUNK + 63) >> 6;
#pragma unroll 1
    for (int tile = w; tile < ntiles; tile += NW) {
        const int c0 = tile * 64;
        int nlive = ((q0 + 15 - c0) >> 4) + 1;
        nlive = nlive > 4 ? 4 : nlive;

        float sc[4][4];
        float pv[4][4];
#pragma unroll
        for (int t4 = 0; t4 < 4; ++t4)
#pragma unroll
            for (int r = 0; r < 4; ++r) pv[t4][r] = 0.f;

        float tmax = -1e30f;
#pragma unroll
        for (int t4 = 0; t4 < 4; ++t4) {
            if (t4 < nlive) {
                f32x4 st = (f32x4)0.0f;
#pragma unroll
                for (int dc = 0; dc < 2; ++dc) {
                    const float* kp = &Kw[(size_t)(b * SEQ + c0 + 16 * t4 + c) * HEAD + dc * 32 + 8 * g];
                    float4 a = *(const float4*)kp;
                    float4 bb = *(const float4*)(kp + 4);
                    float xs[8] = {a.x, a.y, a.z, a.w, bb.x, bb.y, bb.z, bb.w};
                    short8 khi, klo;
#pragma unroll
                    for (int e = 0; e < 8; ++e) {
                        unsigned short h = f2bf(xs[e]);
                        khi[e] = (short)h;
                        klo[e] = (short)f2bf(xs[e] - bf2f(h));
                    }
                    st = __builtin_amdgcn_mfma_f32_16x16x32_bf16(khi, qhi[dc], st, 0, 0, 0);
                    st = __builtin_amdgcn_mfma_f32_16x16x32_bf16(khi, qlo[dc], st, 0, 0, 0);
                    st = __builtin_amdgcn_mfma_f32_16x16x32_bf16(klo, qhi[dc], st, 0, 0, 0);
                }
#pragma unroll
                for (int r = 0; r < 4; ++r) {
                    int kv = c0 + 16 * t4 + 4 * g + r;
                    float s = (kv <= q0 + c) ? st[r] : -1e30f;
                    sc[t4][r] = s;
                    tmax = fmaxf(tmax, s);
                }
            }
        }
        tmax = fmaxf(tmax, __shfl_xor(tmax, 16));
        tmax = fmaxf(tmax, __shfl_xor(tmax, 32));
        float newm = fmaxf(mrun, tmax);
        float corr = __expf(mrun - newm);
        mrun = newm;

        float psum = 0.f;
#pragma unroll
        for (int t4 = 0; t4 < 4; ++t4) {
            if (t4 < nlive) {
#pragma unroll
                for (int r = 0; r < 4; ++r) {
                    float pp = __expf(sc[t4][r] - newm);
                    pv[t4][r] = pp;
                    psum += pp;
                }
            }
        }
        psum += __shfl_xor(psum, 16);
        psum += __shfl_xor(psum, 32);
        lsum = lsum * corr + psum;

        // rescale accumulator rows (q = 4g+r) by corr of that q (held by lane 4g+r)
#pragma unroll
        for (int r = 0; r < 4; ++r) {
            float cq = __shfl(corr, 4 * g + r);
#pragma unroll
            for (int dt = 0; dt < 4; ++dt) acc[dt][r] *= cq;
        }

        // P -> LDS (bf16), per-wave region; zeros for dead sub-tiles
#pragma unroll
        for (int t4 = 0; t4 < 4; ++t4) {
            uint2 u;
            u.x = (unsigned)f2bf(pv[t4][0]) | ((unsigned)f2bf(pv[t4][1]) << 16);
            u.y = (unsigned)f2bf(pv[t4][2]) | ((unsigned)f2bf(pv[t4][3]) << 16);
            *(uint2*)&Plds[w][c][16 * t4 + 4 * g] = u;
        }

        const int nkvc = (nlive + 1) >> 1;
#pragma unroll
        for (int kvc = 0; kvc < 2; ++kvc) {
            if (kvc < nkvc) {
                short8 pf = *(short8*)&Plds[w][c][kvc * 32 + 8 * g];
#pragma unroll
                for (int dt = 0; dt < 4; ++dt) {
                    const unsigned short* vp =
                        &Vt[((size_t)(b * HEAD) + 16 * dt + c) * SEQ + c0 + kvc * 32 + 8 * g];
                    short8 vf = *(const short8*)vp;
                    acc[dt] = __builtin_amdgcn_mfma_f32_16x16x32_bf16(pf, vf, acc[dt], 0, 0, 0);
                }
            }
        }
    }

    // publish partials
    if (g == 0) { Pm[w][c] = mrun; Pl[w][c] = lsum; }
#pragma unroll
    for (int dt = 0; dt < 4; ++dt)
#pragma unroll
        for (int r = 0; r < 4; ++r)
            Po[w][4 * g + r][16 * dt + c] = acc[dt][r];
    __syncthreads();

    // merge: thread t -> row mr = t>>4, dims md..md+3
    const int mr = t >> 4;
    const int md = (t & 15) * 4;
    float M = Pm[0][mr];
#pragma unroll
    for (int ww = 1; ww < NW; ++ww) M = fmaxf(M, Pm[ww][mr]);
    float L = 0.f;
    float4 O; O.x = O.y = O.z = O.w = 0.f;
#pragma unroll
    for (int ww = 0; ww < NW; ++ww) {
        float f = __expf(Pm[ww][mr] - M);
        L += f * Pl[ww][mr];
        float4 p = *(const float4*)&Po[ww][mr][md];
        O.x += f * p.x; O.y += f * p.y; O.z += f * p.z; O.w += f * p.w;
    }
    float inv = 1.0f / L;
    float4 res; res.x = O.x * inv; res.y = O.y * inv; res.z = O.z * inv; res.w = O.w * inv;
    *(float4*)&out[(size_t)(b * SEQ + q0 + mr) * HEAD + md] = res;
}

extern "C" void kernel_launch(void* const* d_in, const int* in_sizes, int n_in,
                              void* d_out, int out_size, void* d_ws, size_t ws_size,
                              hipStream_t stream) {
    (void)in_sizes; (void)n_in; (void)out_size; (void)ws_size;
    const float* x  = (const float*)d_in[0];
    const float* wq = (const float*)d_in[1];
    const float* bq = (const float*)d_in[2];
    const float* wk = (const float*)d_in[3];
    const float* bk = (const float*)d_in[4];
    const float* wv = (const float*)d_in[5];
    const float* bv = (const float*)d_in[6];
    float* out = (float*)d_out;

    float* Qw = (float*)d_ws;                        // [M_TOT][64] fp32
    float* Kw = Qw + (size_t)M_TOT * HEAD;           // [M_TOT][64] fp32
    float* Vw = Kw + (size_t)M_TOT * HEAD;           // [M_TOT][64] fp32
    unsigned short* Vt = (unsigned short*)(Vw + (size_t)M_TOT * HEAD);  // [B][64][S] bf16 (1 MB)

    hipLaunchKernelGGL(qkv_proj_kernel, dim3(M_TOT / BMR), dim3(256), 0, stream,
                       x, wq, bq, wk, bk, wv, bv, Qw, Kw, Vw);
    hipLaunchKernelGGL(vt_kernel, dim3(SEQ / 64, BATCH), dim3(256), 0, stream, Vw, Vt);
    hipLaunchKernelGGL(attn_kernel, dim3(SEQ / CHUNK, BATCH), dim3(256), 0, stream,
                       Qw, Kw, Vt, out);
}

// Round 5
// 120.071 us; speedup vs baseline: 5.8815x; 1.0075x over previous
//
#include <hip/hip_runtime.h>
#include <math.h>

#define D_MODEL 1024
#define HEAD 64
#define BATCH 4
#define SEQ 2048
#define M_TOT (BATCH*SEQ)   // 8192

typedef short short8 __attribute__((ext_vector_type(8)));
typedef float f32x4 __attribute__((ext_vector_type(4)));
typedef unsigned short ushort_t;

__device__ __forceinline__ unsigned short f2bf(float x) {       // round-nearest-even-ish
    union { float f; unsigned u; } v; v.f = x;
    unsigned r = (v.u + 0x7FFFu + ((v.u >> 16) & 1u)) >> 16;
    return (unsigned short)r;
}
__device__ __forceinline__ unsigned short f2bf_trunc(float x) { // truncate mantissa
    union { float f; unsigned u; } v; v.f = x;
    return (unsigned short)(v.u >> 16);
}
__device__ __forceinline__ float bf2f(unsigned short h) {
    union { unsigned u; float f; } v; v.u = ((unsigned)h) << 16;
    return v.f;
}

// ---------------- W split prep: fp32 [1024][64]x3 -> bf16 hi/lo frag layout --
// Frag layout: Wf[((ks*12 + nt)*64 + lane)*8 + e], nt: 0-3=Q, 4-7=K, 8-11=V.
// lane=(c,g): col = (nt&3)*16 + c, k = 32*ks + 8*g + e.
__global__ __launch_bounds__(256) void wsplit_kernel(
    const float* __restrict__ wq, const float* __restrict__ wk,
    const float* __restrict__ wv,
    ushort_t* __restrict__ Wfhi, ushort_t* __restrict__ Wflo)
{
    int tid = blockIdx.x * 256 + threadIdx.x;      // 0..24575
    int l = tid & 63;
    int c = l & 15, g = l >> 4;
    int rest = tid >> 6;
    int nt = rest % 12, ks = rest / 12;
    const float* W = (nt < 4) ? wq : ((nt < 8) ? wk : wv);
    int colm = ((nt & 3) * 16) + c;
    short8 hi, lo;
#pragma unroll
    for (int e = 0; e < 8; ++e) {
        float v = W[(size_t)(32 * ks + 8 * g + e) * HEAD + colm];
        unsigned short h = f2bf_trunc(v);
        hi[e] = (short)h;
        lo[e] = (short)f2bf(v - bf2f(h));
    }
    *(short8*)&Wfhi[(size_t)tid * 8] = hi;
    *(short8*)&Wflo[(size_t)tid * 8] = lo;
}

// ---------------- QKV projection (MFMA split-bf16) ----------------
// Block = 128 thr = 2 waves, one 16-row m-tile; wave w does col-tiles 6w..6w+5.
// Grid = 512 blocks (2 blocks/CU). Outputs: Qhi/Qlo ((q+bq)*8 split),
// Khi/Klo (k+bk split), Vt bf16 [B][64][S].
__global__ __launch_bounds__(128) void proj_kernel(
    const float* __restrict__ x,
    const ushort_t* __restrict__ Wfhi, const ushort_t* __restrict__ Wflo,
    const float* __restrict__ bq, const float* __restrict__ bk,
    const float* __restrict__ bv,
    ushort_t* __restrict__ Qhi, ushort_t* __restrict__ Qlo,
    ushort_t* __restrict__ Khi, ushort_t* __restrict__ Klo,
    ushort_t* __restrict__ Vt)
{
    __shared__ float ld[16][201];
    const int t = threadIdx.x;
    const int w = t >> 6;
    const int l = t & 63;
    const int c = l & 15, g = l >> 4;
    const int m0 = blockIdx.x * 16;

    f32x4 acc[6];
#pragma unroll
    for (int j = 0; j < 6; ++j) acc[j] = (f32x4)0.0f;

    const float* xrow = &x[(size_t)(m0 + c) * D_MODEL + 8 * g];

    for (int ks = 0; ks < 32; ++ks) {
        const float* xp = xrow + 32 * ks;
        float4 a = *(const float4*)xp;
        float4 b2 = *(const float4*)(xp + 4);
        float xs[8] = {a.x, a.y, a.z, a.w, b2.x, b2.y, b2.z, b2.w};
        short8 ahi, alo;
#pragma unroll
        for (int e = 0; e < 8; ++e) {
            unsigned short h = f2bf_trunc(xs[e]);
            ahi[e] = (short)h;
            alo[e] = (short)f2bf_trunc(xs[e] - bf2f(h));
        }
        const size_t fbase = ((size_t)ks * 12 + 6 * w) * 64 + l;
#pragma unroll
        for (int j = 0; j < 6; ++j) {
            short8 bh = *(const short8*)&Wfhi[(fbase + (size_t)j * 64) * 8];
            short8 bl = *(const short8*)&Wflo[(fbase + (size_t)j * 64) * 8];
            acc[j] = __builtin_amdgcn_mfma_f32_16x16x32_bf16(ahi, bh, acc[j], 0, 0, 0);
            acc[j] = __builtin_amdgcn_mfma_f32_16x16x32_bf16(alo, bh, acc[j], 0, 0, 0);
            acc[j] = __builtin_amdgcn_mfma_f32_16x16x32_bf16(ahi, bl, acc[j], 0, 0, 0);
        }
    }

    // stage D tiles: lane holds rows 4g+r, col (6w+j)*16+c
#pragma unroll
    for (int j = 0; j < 6; ++j)
#pragma unroll
        for (int r = 0; r < 4; ++r)
            ld[4 * g + r][(6 * w + j) * 16 + c] = acc[j][r];
    __syncthreads();

    const int b = m0 >> 11;
    const int s0 = m0 & 2047;

    // Q: rows 16 x cols 64; thread: row=t>>3, cols 8*(t&7)..+8
    {
        int row = t >> 3, cs = (t & 7) * 8;
        short8 hi, lo;
#pragma unroll
        for (int i = 0; i < 8; ++i) {
            float v = (ld[row][cs + i] + bq[cs + i]) * 8.0f;
            unsigned short h = f2bf_trunc(v);
            hi[i] = (short)h;
            lo[i] = (short)f2bf(v - bf2f(h));
        }
        *(short8*)&Qhi[(size_t)(m0 + row) * HEAD + cs] = hi;
        *(short8*)&Qlo[(size_t)(m0 + row) * HEAD + cs] = lo;
    }
    // K
    {
        int row = t >> 3, cs = (t & 7) * 8;
        short8 hi, lo;
#pragma unroll
        for (int i = 0; i < 8; ++i) {
            float v = ld[row][64 + cs + i] + bk[cs + i];
            unsigned short h = f2bf_trunc(v);
            hi[i] = (short)h;
            lo[i] = (short)f2bf(v - bf2f(h));
        }
        *(short8*)&Khi[(size_t)(m0 + row) * HEAD + cs] = hi;
        *(short8*)&Klo[(size_t)(m0 + row) * HEAD + cs] = lo;
    }
    // V -> Vt[b][d][s]: thread: d=t>>1, s chunk 8*(t&1)..+8
    {
        int d = t >> 1, sh = (t & 1) * 8;
        float bb = bv[d];
        short8 vv;
#pragma unroll
        for (int i = 0; i < 8; ++i)
            vv[i] = (short)f2bf(ld[sh + i][128 + d] + bb);
        *(short8*)&Vt[((size_t)b * HEAD + d) * SEQ + s0 + sh] = vv;
    }
}

// ---------------- Flash causal attention (MFMA, split-KV) ------
// Block = 256 thr = 4 waves, one 16-row q-chunk; wave w does KV64 tiles w, w+4,...
// Q/K read pre-split bf16 hi/lo; V^T pre-transposed bf16.
#define NW 4
#define CHUNK 16

__global__ __launch_bounds__(256) void attn_kernel(
    const ushort_t* __restrict__ Qhi, const ushort_t* __restrict__ Qlo,
    const ushort_t* __restrict__ Khi, const ushort_t* __restrict__ Klo,
    const ushort_t* __restrict__ Vt, float* __restrict__ out)
{
    __shared__ float Po[NW][CHUNK][68];
    __shared__ float Pm[NW][CHUNK];
    __shared__ float Pl[NW][CHUNK];
    __shared__ __align__(16) ushort_t Plds[NW][CHUNK][72];

    const int t = threadIdx.x;
    const int w = t >> 6;
    const int l = t & 63;
    const int b = blockIdx.y;
    const int chunk = (int)gridDim.x - 1 - (int)blockIdx.x;  // biggest first
    const int q0 = chunk * CHUNK;
    const int c = l & 15;
    const int g = l >> 4;

    short8 qhi[2], qlo[2];
    {
        const ushort_t* qbase = &Qhi[(size_t)(b * SEQ + q0 + c) * HEAD];
        const ushort_t* qbasel = &Qlo[(size_t)(b * SEQ + q0 + c) * HEAD];
#pragma unroll
        for (int dc = 0; dc < 2; ++dc) {
            qhi[dc] = *(const short8*)&qbase[dc * 32 + 8 * g];
            qlo[dc] = *(const short8*)&qbasel[dc * 32 + 8 * g];
        }
    }

    f32x4 acc[4];
#pragma unroll
    for (int dt = 0; dt < 4; ++dt) acc[dt] = (f32x4)0.0f;
    float mrun = -1e30f, lsum = 0.f;

    const int ntiles = (q0 + CHUNK + 63) >> 6;
#pragma unroll 1
    for (int tile = w; tile < ntiles; tile += NW) {
        const int c0 = tile * 64;
        int nlive = ((q0 + 15 - c0) >> 4) + 1;
        nlive = nlive > 4 ? 4 : nlive;

        float sc[4][4];
        float pv[4][4];
#pragma unroll
        for (int t4 = 0; t4 < 4; ++t4)
#pragma unroll
            for (int r = 0; r < 4; ++r) pv[t4][r] = 0.f;

        float tmax = -1e30f;
#pragma unroll
        for (int t4 = 0; t4 < 4; ++t4) {
            if (t4 < nlive) {
                f32x4 st = (f32x4)0.0f;
                const size_t krow = (size_t)(b * SEQ + c0 + 16 * t4 + c) * HEAD;
#pragma unroll
                for (int dc = 0; dc < 2; ++dc) {
                    short8 khi = *(const short8*)&Khi[krow + dc * 32 + 8 * g];
                    short8 klo = *(const short8*)&Klo[krow + dc * 32 + 8 * g];
                    st = __builtin_amdgcn_mfma_f32_16x16x32_bf16(khi, qhi[dc], st, 0, 0, 0);
                    st = __builtin_amdgcn_mfma_f32_16x16x32_bf16(khi, qlo[dc], st, 0, 0, 0);
                    st = __builtin_amdgcn_mfma_f32_16x16x32_bf16(klo, qhi[dc], st, 0, 0, 0);
                }
#pragma unroll
                for (int r = 0; r < 4; ++r) {
                    int kv = c0 + 16 * t4 + 4 * g + r;
                    float s = (kv <= q0 + c) ? st[r] : -1e30f;
                    sc[t4][r] = s;
                    tmax = fmaxf(tmax, s);
                }
            }
        }
        tmax = fmaxf(tmax, __shfl_xor(tmax, 16));
        tmax = fmaxf(tmax, __shfl_xor(tmax, 32));
        float newm = fmaxf(mrun, tmax);
        float corr = __expf(mrun - newm);
        mrun = newm;

        float psum = 0.f;
#pragma unroll
        for (int t4 = 0; t4 < 4; ++t4) {
            if (t4 < nlive) {
#pragma unroll
                for (int r = 0; r < 4; ++r) {
                    float pp = __expf(sc[t4][r] - newm);
                    pv[t4][r] = pp;
                    psum += pp;
                }
            }
        }
        psum += __shfl_xor(psum, 16);
        psum += __shfl_xor(psum, 32);
        lsum = lsum * corr + psum;

#pragma unroll
        for (int r = 0; r < 4; ++r) {
            float cq = __shfl(corr, 4 * g + r);
#pragma unroll
            for (int dt = 0; dt < 4; ++dt) acc[dt][r] *= cq;
        }

#pragma unroll
        for (int t4 = 0; t4 < 4; ++t4) {
            uint2 u;
            u.x = (unsigned)f2bf(pv[t4][0]) | ((unsigned)f2bf(pv[t4][1]) << 16);
            u.y = (unsigned)f2bf(pv[t4][2]) | ((unsigned)f2bf(pv[t4][3]) << 16);
            *(uint2*)&Plds[w][c][16 * t4 + 4 * g] = u;
        }

        const int nkvc = (nlive + 1) >> 1;
#pragma unroll
        for (int kvc = 0; kvc < 2; ++kvc) {
            if (kvc < nkvc) {
                short8 pf = *(short8*)&Plds[w][c][kvc * 32 + 8 * g];
#pragma unroll
                for (int dt = 0; dt < 4; ++dt) {
                    const ushort_t* vp =
                        &Vt[((size_t)(b * HEAD) + 16 * dt + c) * SEQ + c0 + kvc * 32 + 8 * g];
                    short8 vf = *(const short8*)vp;
                    acc[dt] = __builtin_amdgcn_mfma_f32_16x16x32_bf16(pf, vf, acc[dt], 0, 0, 0);
                }
            }
        }
    }

    if (g == 0) { Pm[w][c] = mrun; Pl[w][c] = lsum; }
#pragma unroll
    for (int dt = 0; dt < 4; ++dt)
#pragma unroll
        for (int r = 0; r < 4; ++r)
            Po[w][4 * g + r][16 * dt + c] = acc[dt][r];
    __syncthreads();

    const int mr = t >> 4;
    const int md = (t & 15) * 4;
    float M = Pm[0][mr];
#pragma unroll
    for (int ww = 1; ww < NW; ++ww) M = fmaxf(M, Pm[ww][mr]);
    float L = 0.f;
    float4 O; O.x = O.y = O.z = O.w = 0.f;
#pragma unroll
    for (int ww = 0; ww < NW; ++ww) {
        float f = __expf(Pm[ww][mr] - M);
        L += f * Pl[ww][mr];
        float4 p = *(const float4*)&Po[ww][mr][md];
        O.x += f * p.x; O.y += f * p.y; O.z += f * p.z; O.w += f * p.w;
    }
    float inv = 1.0f / L;
    float4 res; res.x = O.x * inv; res.y = O.y * inv; res.z = O.z * inv; res.w = O.w * inv;
    *(float4*)&out[(size_t)(b * SEQ + q0 + mr) * HEAD + md] = res;
}

extern "C" void kernel_launch(void* const* d_in, const int* in_sizes, int n_in,
                              void* d_out, int out_size, void* d_ws, size_t ws_size,
                              hipStream_t stream) {
    (void)in_sizes; (void)n_in; (void)out_size; (void)ws_size;
    const float* x  = (const float*)d_in[0];
    const float* wq = (const float*)d_in[1];
    const float* bq = (const float*)d_in[2];
    const float* wk = (const float*)d_in[3];
    const float* bk = (const float*)d_in[4];
    const float* wv = (const float*)d_in[5];
    const float* bv = (const float*)d_in[6];
    float* out = (float*)d_out;

    ushort_t* Wfhi = (ushort_t*)d_ws;                        // 384 KB (196608 shorts)
    ushort_t* Wflo = Wfhi + (size_t)D_MODEL * 192;           // 384 KB
    ushort_t* Qhi  = Wflo + (size_t)D_MODEL * 192;           // 1 MB each
    ushort_t* Qlo  = Qhi + (size_t)M_TOT * HEAD;
    ushort_t* Khi  = Qlo + (size_t)M_TOT * HEAD;
    ushort_t* Klo  = Khi + (size_t)M_TOT * HEAD;
    ushort_t* Vt   = Klo + (size_t)M_TOT * HEAD;             // [B][64][S]

    hipLaunchKernelGGL(wsplit_kernel, dim3(96), dim3(256), 0, stream,
                       wq, wk, wv, Wfhi, Wflo);
    hipLaunchKernelGGL(proj_kernel, dim3(M_TOT / 16), dim3(128), 0, stream,
                       x, Wfhi, Wflo, bq, bk, bv, Qhi, Qlo, Khi, Klo, Vt);
    hipLaunchKernelGGL(attn_kernel, dim3(SEQ / CHUNK, BATCH), dim3(256), 0, stream,
                       Qhi, Qlo, Khi, Klo, Vt, out);
}

// Round 7
// 91.268 us; speedup vs baseline: 7.7376x; 1.3156x over previous
//
#include <hip/hip_runtime.h>
#include <math.h>

#define D_MODEL 1024
#define HEAD 64
#define BATCH 4
#define SEQ 2048
#define M_TOT (BATCH*SEQ)   // 8192

typedef short short8 __attribute__((ext_vector_type(8)));
typedef float f32x4 __attribute__((ext_vector_type(4)));
typedef unsigned short ushort_t;

__device__ __forceinline__ unsigned short f2bf(float x) {       // round-to-nearest
    union { float f; unsigned u; } v; v.f = x;
    unsigned r = (v.u + 0x7FFFu + ((v.u >> 16) & 1u)) >> 16;
    return (unsigned short)r;
}
__device__ __forceinline__ unsigned short f2bf_trunc(float x) { // truncate mantissa
    union { float f; unsigned u; } v; v.f = x;
    return (unsigned short)(v.u >> 16);
}
__device__ __forceinline__ float bf2f(unsigned short h) {
    union { unsigned u; float f; } v; v.u = ((unsigned)h) << 16;
    return v.f;
}

// ---------------- W split prep: fp32 [1024][64]x3 -> bf16 hi/lo frag layout --
// Wf[((ks*12 + nt)*64 + l)*8 + e], nt: 0-3=Q, 4-7=K, 8-11=V.
// lane l=(c,g): col = (nt&3)*16 + c, k = 32*ks + 8*g + e.
__global__ __launch_bounds__(256) void wsplit_kernel(
    const float* __restrict__ wq, const float* __restrict__ wk,
    const float* __restrict__ wv,
    ushort_t* __restrict__ Wfhi, ushort_t* __restrict__ Wflo)
{
    int tid = blockIdx.x * 256 + threadIdx.x;      // 0..24575
    int l = tid & 63;
    int c = l & 15, g = l >> 4;
    int rest = tid >> 6;
    int nt = rest % 12, ks = rest / 12;
    const float* W = (nt < 4) ? wq : ((nt < 8) ? wk : wv);
    int colm = ((nt & 3) * 16) + c;
    short8 hi, lo;
#pragma unroll
    for (int e = 0; e < 8; ++e) {
        float v = W[(size_t)(32 * ks + 8 * g + e) * HEAD + colm];
        unsigned short h = f2bf_trunc(v);
        hi[e] = (short)h;
        lo[e] = (short)f2bf(v - bf2f(h));
    }
    *(short8*)&Wfhi[(size_t)tid * 8] = hi;
    *(short8*)&Wflo[(size_t)tid * 8] = lo;
}

// ---------------- QKV projection (MFMA split-bf16, 1 wave per job) --------
// Job = (mt, ntg): 16-row m-tile x 2 col-tiles (32 cols of one matrix).
// ntg: 0,1 -> Q cols 0-31/32-63; 2,3 -> K; 4,5 -> V.  3072 jobs = 12 waves/CU.
// x is converted fp32 -> bf16 hi/lo on the fly (no big scratch buffers).
__global__ __launch_bounds__(256) void proj_kernel(
    const float* __restrict__ x,
    const ushort_t* __restrict__ Wfhi, const ushort_t* __restrict__ Wflo,
    const float* __restrict__ bq, const float* __restrict__ bk,
    const float* __restrict__ bv,
    ushort_t* __restrict__ Qhi, ushort_t* __restrict__ Qlo,
    ushort_t* __restrict__ Khi, ushort_t* __restrict__ Klo,
    ushort_t* __restrict__ Vt)
{
    __shared__ float ld[4][16][33];
    const int t = threadIdx.x;
    const int w = t >> 6;
    const int l = t & 63;
    const int c = l & 15, g = l >> 4;
    const int job = blockIdx.x * 4 + w;
    const int mt = job / 6;
    const int ntg = job - mt * 6;
    const int m0 = mt * 16;

    f32x4 acc0 = (f32x4)0.0f, acc1 = (f32x4)0.0f;

    const float* xrow = &x[(size_t)(m0 + c) * D_MODEL + 8 * g];
    const size_t wbase = (size_t)(ntg * 2) * 512 + (size_t)l * 8;

#pragma unroll 4
    for (int ks = 0; ks < 32; ++ks) {
        const float* xp = xrow + 32 * ks;
        float4 a = *(const float4*)xp;
        float4 b2 = *(const float4*)(xp + 4);
        float xs[8] = {a.x, a.y, a.z, a.w, b2.x, b2.y, b2.z, b2.w};
        short8 xh, xl;
#pragma unroll
        for (int e = 0; e < 8; ++e) {
            unsigned short h = f2bf_trunc(xs[e]);
            xh[e] = (short)h;
            xl[e] = (short)f2bf(xs[e] - bf2f(h));
        }
        const size_t wo = wbase + (size_t)ks * 6144;
        short8 wh0 = *(const short8*)&Wfhi[wo];
        short8 wl0 = *(const short8*)&Wflo[wo];
        short8 wh1 = *(const short8*)&Wfhi[wo + 512];
        short8 wl1 = *(const short8*)&Wflo[wo + 512];
        acc0 = __builtin_amdgcn_mfma_f32_16x16x32_bf16(xh, wh0, acc0, 0, 0, 0);
        acc1 = __builtin_amdgcn_mfma_f32_16x16x32_bf16(xh, wh1, acc1, 0, 0, 0);
        acc0 = __builtin_amdgcn_mfma_f32_16x16x32_bf16(xl, wh0, acc0, 0, 0, 0);
        acc1 = __builtin_amdgcn_mfma_f32_16x16x32_bf16(xl, wh1, acc1, 0, 0, 0);
        acc0 = __builtin_amdgcn_mfma_f32_16x16x32_bf16(xh, wl0, acc0, 0, 0, 0);
        acc1 = __builtin_amdgcn_mfma_f32_16x16x32_bf16(xh, wl1, acc1, 0, 0, 0);
    }

    // stage D: lane holds rows 4g+r, lds col = c / 16+c (matrix col = 32*(ntg&1)+lds_col)
#pragma unroll
    for (int r = 0; r < 4; ++r) {
        ld[w][4 * g + r][c] = acc0[r];
        ld[w][4 * g + r][16 + c] = acc1[r];
    }
    // same-wave DS ordering: no barrier needed (per-wave LDS region)

    const int b = m0 >> 11;
    const int s0 = m0 & 2047;
    const int cb32 = (ntg & 1) * 32;

    if (ntg < 4) {
        // Q or K: thread: row = l>>2, col-chunk cc = 8*(l&3) within the 32
        const int row = l >> 2, cc = (l & 3) * 8;
        const float* bias = (ntg < 2) ? bq : bk;
        const float scale = (ntg < 2) ? 8.0f : 1.0f;
        ushort_t* Dhi = (ntg < 2) ? Qhi : Khi;
        ushort_t* Dlo = (ntg < 2) ? Qlo : Klo;
        short8 hi, lo;
#pragma unroll
        for (int i = 0; i < 8; ++i) {
            float v = (ld[w][row][cc + i] + bias[cb32 + cc + i]) * scale;
            unsigned short h = f2bf_trunc(v);
            hi[i] = (short)h;
            lo[i] = (short)f2bf(v - bf2f(h));
        }
        *(short8*)&Dhi[(size_t)(m0 + row) * HEAD + cb32 + cc] = hi;
        *(short8*)&Dlo[(size_t)(m0 + row) * HEAD + cb32 + cc] = lo;
    } else {
        // V -> Vt[b][d][s]: thread: d_local = l>>1, s-chunk = (l&1)*8
        const int dl = l >> 1, sh = (l & 1) * 8;
        const float bb = bv[cb32 + dl];
        short8 vv;
#pragma unroll
        for (int i = 0; i < 8; ++i)
            vv[i] = (short)f2bf(ld[w][sh + i][dl] + bb);
        *(short8*)&Vt[((size_t)b * HEAD + cb32 + dl) * SEQ + s0 + sh] = vv;
    }
}

// ---------------- Flash causal attention (MFMA, split-KV) ------
#define NW 4
#define CHUNK 16

__global__ __launch_bounds__(256) void attn_kernel(
    const ushort_t* __restrict__ Qhi, const ushort_t* __restrict__ Qlo,
    const ushort_t* __restrict__ Khi, const ushort_t* __restrict__ Klo,
    const ushort_t* __restrict__ Vt, float* __restrict__ out)
{
    __shared__ float Po[NW][CHUNK][68];
    __shared__ float Pm[NW][CHUNK];
    __shared__ float Pl[NW][CHUNK];
    __shared__ __align__(16) ushort_t Plds[NW][CHUNK][72];

    const int t = threadIdx.x;
    const int w = t >> 6;
    const int l = t & 63;
    const int b = blockIdx.y;
    const int chunk = (int)gridDim.x - 1 - (int)blockIdx.x;  // biggest first
    const int q0 = chunk * CHUNK;
    const int c = l & 15;
    const int g = l >> 4;

    short8 qhi[2], qlo[2];
    {
        const ushort_t* qbase = &Qhi[(size_t)(b * SEQ + q0 + c) * HEAD];
        const ushort_t* qbasel = &Qlo[(size_t)(b * SEQ + q0 + c) * HEAD];
#pragma unroll
        for (int dc = 0; dc < 2; ++dc) {
            qhi[dc] = *(const short8*)&qbase[dc * 32 + 8 * g];
            qlo[dc] = *(const short8*)&qbasel[dc * 32 + 8 * g];
        }
    }

    f32x4 acc[4];
#pragma unroll
    for (int dt = 0; dt < 4; ++dt) acc[dt] = (f32x4)0.0f;
    float mrun = -1e30f, lsum = 0.f;

    const int ntiles = (q0 + CHUNK + 63) >> 6;
#pragma unroll 1
    for (int tile = w; tile < ntiles; tile += NW) {
        const int c0 = tile * 64;
        int nlive = ((q0 + 15 - c0) >> 4) + 1;
        nlive = nlive > 4 ? 4 : nlive;

        float sc[4][4];
        float pv[4][4];
#pragma unroll
        for (int t4 = 0; t4 < 4; ++t4)
#pragma unroll
            for (int r = 0; r < 4; ++r) pv[t4][r] = 0.f;

        float tmax = -1e30f;
#pragma unroll
        for (int t4 = 0; t4 < 4; ++t4) {
            if (t4 < nlive) {
                f32x4 st = (f32x4)0.0f;
                const size_t krow = (size_t)(b * SEQ + c0 + 16 * t4 + c) * HEAD;
#pragma unroll
                for (int dc = 0; dc < 2; ++dc) {
                    short8 khi = *(const short8*)&Khi[krow + dc * 32 + 8 * g];
                    short8 klo = *(const short8*)&Klo[krow + dc * 32 + 8 * g];
                    st = __builtin_amdgcn_mfma_f32_16x16x32_bf16(khi, qhi[dc], st, 0, 0, 0);
                    st = __builtin_amdgcn_mfma_f32_16x16x32_bf16(khi, qlo[dc], st, 0, 0, 0);
                    st = __builtin_amdgcn_mfma_f32_16x16x32_bf16(klo, qhi[dc], st, 0, 0, 0);
                }
#pragma unroll
                for (int r = 0; r < 4; ++r) {
                    int kv = c0 + 16 * t4 + 4 * g + r;
                    float s = (kv <= q0 + c) ? st[r] : -1e30f;
                    sc[t4][r] = s;
                    tmax = fmaxf(tmax, s);
                }
            }
        }
        tmax = fmaxf(tmax, __shfl_xor(tmax, 16));
        tmax = fmaxf(tmax, __shfl_xor(tmax, 32));
        float newm = fmaxf(mrun, tmax);
        float corr = __expf(mrun - newm);
        mrun = newm;

        float psum = 0.f;
#pragma unroll
        for (int t4 = 0; t4 < 4; ++t4) {
            if (t4 < nlive) {
#pragma unroll
                for (int r = 0; r < 4; ++r) {
                    float pp = __expf(sc[t4][r] - newm);
                    pv[t4][r] = pp;
                    psum += pp;
                }
            }
        }
        psum += __shfl_xor(psum, 16);
        psum += __shfl_xor(psum, 32);
        lsum = lsum * corr + psum;

#pragma unroll
        for (int r = 0; r < 4; ++r) {
            float cq = __shfl(corr, 4 * g + r);
#pragma unroll
            for (int dt = 0; dt < 4; ++dt) acc[dt][r] *= cq;
        }

#pragma unroll
        for (int t4 = 0; t4 < 4; ++t4) {
            uint2 u;
            u.x = (unsigned)f2bf(pv[t4][0]) | ((unsigned)f2bf(pv[t4][1]) << 16);
            u.y = (unsigned)f2bf(pv[t4][2]) | ((unsigned)f2bf(pv[t4][3]) << 16);
            *(uint2*)&Plds[w][c][16 * t4 + 4 * g] = u;
        }

        const int nkvc = (nlive + 1) >> 1;
#pragma unroll
        for (int kvc = 0; kvc < 2; ++kvc) {
            if (kvc < nkvc) {
                short8 pf = *(short8*)&Plds[w][c][kvc * 32 + 8 * g];
#pragma unroll
                for (int dt = 0; dt < 4; ++dt) {
                    const ushort_t* vp =
                        &Vt[((size_t)(b * HEAD) + 16 * dt + c) * SEQ + c0 + kvc * 32 + 8 * g];
                    short8 vf = *(const short8*)vp;
                    acc[dt] = __builtin_amdgcn_mfma_f32_16x16x32_bf16(pf, vf, acc[dt], 0, 0, 0);
                }
            }
        }
    }

    if (g == 0) { Pm[w][c] = mrun; Pl[w][c] = lsum; }
#pragma unroll
    for (int dt = 0; dt < 4; ++dt)
#pragma unroll
        for (int r = 0; r < 4; ++r)
            Po[w][4 * g + r][16 * dt + c] = acc[dt][r];
    __syncthreads();

    const int mr = t >> 4;
    const int md = (t & 15) * 4;
    float M = Pm[0][mr];
#pragma unroll
    for (int ww = 1; ww < NW; ++ww) M = fmaxf(M, Pm[ww][mr]);
    float L = 0.f;
    float4 O; O.x = O.y = O.z = O.w = 0.f;
#pragma unroll
    for (int ww = 0; ww < NW; ++ww) {
        float f = __expf(Pm[ww][mr] - M);
        L += f * Pl[ww][mr];
        float4 p = *(const float4*)&Po[ww][mr][md];
        O.x += f * p.x; O.y += f * p.y; O.z += f * p.z; O.w += f * p.w;
    }
    float inv = 1.0f / L;
    float4 res; res.x = O.x * inv; res.y = O.y * inv; res.z = O.z * inv; res.w = O.w * inv;
    *(float4*)&out[(size_t)(b * SEQ + q0 + mr) * HEAD + md] = res;
}

extern "C" void kernel_launch(void* const* d_in, const int* in_sizes, int n_in,
                              void* d_out, int out_size, void* d_ws, size_t ws_size,
                              hipStream_t stream) {
    (void)in_sizes; (void)n_in; (void)out_size; (void)ws_size;
    const float* x  = (const float*)d_in[0];
    const float* wq = (const float*)d_in[1];
    const float* bq = (const float*)d_in[2];
    const float* wk = (const float*)d_in[3];
    const float* bk = (const float*)d_in[4];
    const float* wv = (const float*)d_in[5];
    const float* bv = (const float*)d_in[6];
    float* out = (float*)d_out;

    // workspace layout: 5.75 MB total (validated footprint)
    ushort_t* Wfhi = (ushort_t*)d_ws;                        // 384 KB
    ushort_t* Wflo = Wfhi + (size_t)D_MODEL * 192;           // 384 KB
    ushort_t* Qhi  = Wflo + (size_t)D_MODEL * 192;           // 1 MB each
    ushort_t* Qlo  = Qhi + (size_t)M_TOT * HEAD;
    ushort_t* Khi  = Qlo + (size_t)M_TOT * HEAD;
    ushort_t* Klo  = Khi + (size_t)M_TOT * HEAD;
    ushort_t* Vt   = Klo + (size_t)M_TOT * HEAD;             // [B][64][S], 1 MB

    hipLaunchKernelGGL(wsplit_kernel, dim3(96), dim3(256), 0, stream,
                       wq, wk, wv, Wfhi, Wflo);
    hipLaunchKernelGGL(proj_kernel, dim3(M_TOT / 16 * 6 / 4), dim3(256), 0, stream,
                       x, Wfhi, Wflo, bq, bk, bv, Qhi, Qlo, Khi, Klo, Vt);
    hipLaunchKernelGGL(attn_kernel, dim3(SEQ / CHUNK, BATCH), dim3(256), 0, stream,
                       Qhi, Qlo, Khi, Klo, Vt, out);
}